// Round 6
// baseline (226.813 us; speedup 1.0000x reference)
//
#include <hip/hip_runtime.h>
#include <cmath>

// Temporal Contrast Enhancement — R8: 8-wave fused kernel (occupancy fix).
// R5 post-mortem: named-reg staging killed the spill (WRITE 297->88.6MB,
// k_one 173->106us) but the kernel is latency-bound: 134KB LDS -> 1 block/CU
// -> 1 wave/SIMD, VALUBusy 32%, 68% idle on lgkm/vm/barrier/dep-chains.
// Fix: 512-thread blocks (2 waves/SIMD) at S=24: x-buffers 2x57.3KB + LDS
// Ac/Bc 29.4KB = 144KB; Yd/Ya/Ye live in the global ws (3*3675*256*4 =
// exactly the old 5-array footprint). Per-thread serial work halves too.

typedef float f32x4 __attribute__((ext_vector_type(4)));

static constexpr int   kT  = 88200;
static constexpr float kSR = 44100.0f;

// ---- fused-kernel geometry (512 threads, S=24) ----------------------------
static constexpr int FS_      = 24;                    // chunk length
static constexpr int FNC_     = kT / FS_;              // 3675 chunks/series
static constexpr int FPADS    = FS_ + 4;               // 28 floats (112B, 16B-aligned)
static constexpr int FTH      = 512;                   // threads = chunks/tile
static constexpr int FNT      = (FNC_ + FTH - 1) / FTH;    // 8 tiles
static constexpr int FTAILC   = FNC_ - FTH * (FNT - 1);    // 91
static constexpr int FF4C     = FS_ / 4;               // 6 float4 per chunk
static constexpr int FTILE_F4 = FTH * FF4C;            // 3072
static constexpr int FTAIL_F4 = FTAILC * FF4C;         // 546
static constexpr int FBUF_F   = FTH * FPADS;           // 14336 floats (57.3KB)

struct EnvP { float ad, bd, aa, ba, nuamp, reg; };

__device__ __forceinline__ EnvP make_params(const float* tauA, const float* tauD,
                                            const float* nu, const float* dbreg) {
  EnvP p;
  float td = fminf(fmaxf(tauD[0], 1.0f), 100.0f);
  td = fminf(fmaxf(td, 0.1f), 1000.0f) * 0.001f;
  float ta = fminf(fmaxf(tauA[0], 1.0f), 100.0f);
  ta = fminf(fmaxf(ta, 0.1f), 1000.0f) * 0.001f;
  p.ad = expf(-1.0f / (td * kSR));
  p.aa = expf(-1.0f / (ta * kSR));
  p.bd = 1.0f - p.ad;
  p.ba = 1.0f - p.aa;
  p.nuamp = exp10f(fminf(fmaxf(nu[0],    -60.0f),   0.0f) * 0.05f);
  p.reg   = exp10f(fminf(fmaxf(dbreg[0], -120.0f), -60.0f) * 0.05f);
  return p;
}

// MODE: 0=comp_d  1=comp_a(replay yd)  2=comp_e(replay yd,ya)  3=final
// Ac/Bc in LDS; Ydl/Yal/Yel per-series pointers in GLOBAL ws.
template <int MODE>
__device__ __forceinline__ void sweep(const float* __restrict__ xs,
                                      float* __restrict__ os,
                                      const EnvP& p,
                                      float* __restrict__ buf0,
                                      float* __restrict__ buf1,
                                      float* __restrict__ Ac, float* __restrict__ Bc,
                                      const float* __restrict__ Ydl,
                                      const float* __restrict__ Yal,
                                      const float* __restrict__ Yel,
                                      int t) {
  // Six NAMED staging registers — never an array, never spillable.
  f32x4 r0, r1, r2, r3, r4, r5;
  const f32x4* xg4 = reinterpret_cast<const f32x4*>(xs);

#define LD_TILE(TILE)                                                        \
  do {                                                                       \
    const int nf4_ = ((TILE) == FNT - 1) ? FTAIL_F4 : FTILE_F4;              \
    const f32x4* xg_ = xg4 + (size_t)(TILE) * FTILE_F4;                      \
    int i0_ = t;                                                             \
    r0 = xg_[i0_ < nf4_ ? i0_ : 0];  i0_ += FTH;                             \
    r1 = xg_[i0_ < nf4_ ? i0_ : 0];  i0_ += FTH;                             \
    r2 = xg_[i0_ < nf4_ ? i0_ : 0];  i0_ += FTH;                             \
    r3 = xg_[i0_ < nf4_ ? i0_ : 0];  i0_ += FTH;                             \
    r4 = xg_[i0_ < nf4_ ? i0_ : 0];  i0_ += FTH;                             \
    r5 = xg_[i0_ < nf4_ ? i0_ : 0];                                          \
  } while (0)

#define WR_TILE(BUF)                                                         \
  do {                                                                       \
    float* b_ = (BUF);                                                       \
    int i0_ = t, ch_, of_;                                                   \
    ch_ = i0_ / FF4C; of_ = (i0_ - ch_ * FF4C) * 4;                          \
    *reinterpret_cast<f32x4*>(&b_[ch_ * FPADS + of_]) = r0;  i0_ += FTH;     \
    ch_ = i0_ / FF4C; of_ = (i0_ - ch_ * FF4C) * 4;                          \
    *reinterpret_cast<f32x4*>(&b_[ch_ * FPADS + of_]) = r1;  i0_ += FTH;     \
    ch_ = i0_ / FF4C; of_ = (i0_ - ch_ * FF4C) * 4;                          \
    *reinterpret_cast<f32x4*>(&b_[ch_ * FPADS + of_]) = r2;  i0_ += FTH;     \
    ch_ = i0_ / FF4C; of_ = (i0_ - ch_ * FF4C) * 4;                          \
    *reinterpret_cast<f32x4*>(&b_[ch_ * FPADS + of_]) = r3;  i0_ += FTH;     \
    ch_ = i0_ / FF4C; of_ = (i0_ - ch_ * FF4C) * 4;                          \
    *reinterpret_cast<f32x4*>(&b_[ch_ * FPADS + of_]) = r4;  i0_ += FTH;     \
    ch_ = i0_ / FF4C; of_ = (i0_ - ch_ * FF4C) * 4;                          \
    *reinterpret_cast<f32x4*>(&b_[ch_ * FPADS + of_]) = r5;                  \
  } while (0)

  LD_TILE(0);
  WR_TILE(buf0);
  __syncthreads();
  int cur = 0;
  for (int it = 0; it < FNT; ++it) {
    const bool pf = (it + 1 < FNT);
    if (pf) LD_TILE(it + 1);                  // issue next-tile loads NOW
    __builtin_amdgcn_sched_barrier(0);        // pin issue before compute
    float* bc = cur ? buf1 : buf0;
    float* bn = cur ? buf0 : buf1;
    const int c = it * FTH + t;
    if (c < FNC_) {
      float* my = &bc[t * FPADS];
      if (MODE == 0) {
        float A = -INFINITY, B = 0.0f;
#pragma unroll 2
        for (int i = 0; i < FF4C; ++i) {
          f32x4 v = *reinterpret_cast<const f32x4*>(&my[4 * i]);
#pragma unroll
          for (int j = 0; j < 4; ++j) {
            float xa = fabsf(v[j]);
            float bx = p.bd * xa;
            A = fmaxf(xa, fmaf(p.ad, A, bx));
            B = fmaf(p.ad, B, bx);
          }
        }
        Ac[c] = A; Bc[c] = B;
      } else if (MODE == 1) {
        float yd = Ydl[c];
        float A = INFINITY, B = 0.0f;
#pragma unroll 2
        for (int i = 0; i < FF4C; ++i) {
          f32x4 v = *reinterpret_cast<const f32x4*>(&my[4 * i]);
#pragma unroll
          for (int j = 0; j < 4; ++j) {
            float xa = fabsf(v[j]);
            yd = fmaxf(xa, fmaf(p.ad, yd, p.bd * xa));
            float by = p.ba * yd;
            A = fminf(yd, fmaf(p.aa, A, by));
            B = fmaf(p.aa, B, by);
          }
        }
        Ac[c] = A; Bc[c] = B;
      } else if (MODE == 2) {
        float yd = Ydl[c], ya = Yal[c];
        float A = -INFINITY, B = 0.0f;
#pragma unroll 2
        for (int i = 0; i < FF4C; ++i) {
          f32x4 v = *reinterpret_cast<const f32x4*>(&my[4 * i]);
#pragma unroll
          for (int j = 0; j < 4; ++j) {
            float xa = fabsf(v[j]);
            yd = fmaxf(xa, fmaf(p.ad, yd, p.bd * xa));
            ya = fminf(yd, fmaf(p.aa, ya, p.ba * yd));
            float et = fmaxf((yd - ya) - p.nuamp, 0.0f);
            float bx = p.bd * et;
            A = fmaxf(et, fmaf(p.ad, A, bx));
            B = fmaf(p.ad, B, bx);
          }
        }
        Ac[c] = A; Bc[c] = B;
      } else {
        float yd = Ydl[c], ya = Yal[c], ye = Yel[c];
#pragma unroll 2
        for (int i = 0; i < FF4C; ++i) {
          f32x4 v = *reinterpret_cast<const f32x4*>(&my[4 * i]);
          f32x4 oo;
#pragma unroll
          for (int j = 0; j < 4; ++j) {
            float xa = fabsf(v[j]);
            yd = fmaxf(xa, fmaf(p.ad, yd, p.bd * xa));
            ya = fminf(yd, fmaf(p.aa, ya, p.ba * yd));
            float et = fmaxf((yd - ya) - p.nuamp, 0.0f);
            ye = fmaxf(et, fmaf(p.ad, ye, p.bd * et));
            oo[j] = v[j] * (et / (ye + p.reg));
          }
          *reinterpret_cast<f32x4*>(&my[4 * i]) = oo;
        }
      }
    }
    if (MODE == 3) {
      __syncthreads();                        // results in bc visible to all
      f32x4* og = reinterpret_cast<f32x4*>(os) + (size_t)it * FTILE_F4;
      const int nf4 = pf ? FTILE_F4 : FTAIL_F4;
#pragma unroll
      for (int i = 0; i < FF4C; ++i) {
        int idx = t + i * FTH;
        if (idx < nf4) {
          int chunk = idx / FF4C;
          int off   = (idx - chunk * FF4C) * 4;
          f32x4 v = *reinterpret_cast<const f32x4*>(&bc[chunk * FPADS + off]);
          __builtin_nontemporal_store(v, &og[idx]);   // don't evict x from L3
        }
      }
    }
    if (pf) WR_TILE(bn);                      // vmcnt waits land here
    __syncthreads();
    cur ^= 1;
  }
#undef LD_TILE
#undef WR_TILE
}

// In-block scan over this series' FNC_ chunk summaries (Ac/Bc in LDS),
// writing the per-chunk start values Y to GLOBAL ws (read by later sweeps).
template <int ATTACK>
__device__ __forceinline__ void scan_lds(const float* __restrict__ Ac,
                                         const float* __restrict__ Bc,
                                         float* __restrict__ Y,
                                         const EnvP& p,
                                         float* __restrict__ sbuf, int t) {
  constexpr int CPT = (FNC_ + FTH - 1) / FTH;   // 8
  const float alpha = ATTACK ? p.aa : p.ad;
  const float ID_A  = ATTACK ? INFINITY : -INFINITY;
  const float gS = powf(alpha, (float)FS_);

  float ca[CPT], cb[CPT];
  float a = ID_A, b = 0.0f, g = 1.0f;
#pragma unroll
  for (int k = 0; k < CPT; ++k) {
    int c = t * CPT + k;
    if (c < FNC_) { ca[k] = Ac[c]; cb[k] = Bc[c]; }
    else          { ca[k] = ID_A;  cb[k] = 0.0f; }
    float cg = (c < FNC_) ? gS : 1.0f;
    float na = ATTACK ? fminf(ca[k], fmaf(cg, a, cb[k]))
                      : fmaxf(ca[k], fmaf(cg, a, cb[k]));
    b = fmaf(cg, b, cb[k]);
    g = cg * g;
    a = na;
  }

  float* sA = sbuf; float* sB = sbuf + FTH; float* sG = sbuf + 2 * FTH;
  sA[t] = a; sB[t] = b; sG[t] = g;
  __syncthreads();
#pragma unroll
  for (int d = 1; d < FTH; d <<= 1) {
    float pa = 0.0f, pb = 0.0f, pg = 0.0f;
    if (t >= d) { pa = sA[t - d]; pb = sB[t - d]; pg = sG[t - d]; }
    __syncthreads();
    if (t >= d) {
      float na = ATTACK ? fminf(a, fmaf(g, pa, b)) : fmaxf(a, fmaf(g, pa, b));
      b = fmaf(g, pb, b);
      g = g * pg;
      a = na;
      sA[t] = a; sB[t] = b; sG[t] = g;
    }
    __syncthreads();
  }

  float ea, eb;
  if (t == 0) { ea = ID_A; eb = 0.0f; }
  else        { ea = sA[t - 1]; eb = sB[t - 1]; }

#pragma unroll
  for (int k = 0; k < CPT; ++k) {
    int c = t * CPT + k;
    if (c >= FNC_) break;
    Y[c] = ATTACK ? fminf(ea, eb) : fmaxf(ea, eb);   // eval at y0=0
    float na = ATTACK ? fminf(ca[k], fmaf(gS, ea, cb[k]))
                      : fmaxf(ca[k], fmaf(gS, ea, cb[k]));
    eb = fmaf(gS, eb, cb[k]);
    ea = na;
  }
}

// ---- the fused one-block-per-series kernel (512 threads, 8 waves) ---------
// LDS 144KB -> 1 block/CU -> exactly 2 waves/SIMD; waves_per_eu(2,2) is
// truthful and gives a 256-VGPR budget (no spill of the named staging regs).
__global__
__attribute__((amdgpu_flat_work_group_size(512, 512), amdgpu_waves_per_eu(2, 2)))
void k_one(const float* __restrict__ x,
           const float* tauA, const float* tauD,
           const float* nu, const float* dbreg,
           float* __restrict__ Ydg, float* __restrict__ Yag,
           float* __restrict__ Yeg,
           float* __restrict__ out) {
  extern __shared__ float lds[];
  float* buf0 = lds;                          // 14336 f
  float* buf1 = lds + FBUF_F;                 // 14336 f
  float* Ac   = lds + 2 * FBUF_F;             // 3675 f
  float* Bc   = Ac + FNC_;                    // 3675 f  -> total 144088 B
  const int t = threadIdx.x;
  const int s = blockIdx.x;
  const float* xs = x   + (size_t)s * kT;
  float*       os = out + (size_t)s * kT;
  float* Yd = Ydg + (size_t)s * FNC_;
  float* Ya = Yag + (size_t)s * FNC_;
  float* Ye = Yeg + (size_t)s * FNC_;
  EnvP p = make_params(tauA, tauD, nu, dbreg);

  sweep<0>(xs, nullptr, p, buf0, buf1, Ac, Bc, nullptr, nullptr, nullptr, t);
  scan_lds<0>(Ac, Bc, Yd, p, buf0, t);        // buf0 free between sweeps
  __syncthreads();
  sweep<1>(xs, nullptr, p, buf0, buf1, Ac, Bc, Yd, nullptr, nullptr, t);
  scan_lds<1>(Ac, Bc, Ya, p, buf0, t);
  __syncthreads();
  sweep<2>(xs, nullptr, p, buf0, buf1, Ac, Bc, Yd, Ya, nullptr, t);
  scan_lds<0>(Ac, Bc, Ye, p, buf0, t);
  __syncthreads();
  sweep<3>(xs, os, p, buf0, buf1, Ac, Bc, Yd, Ya, Ye, t);
}

// ---- Fallback: the verified 235us 7-kernel pipeline -----------------------
template <int FS, int MODE>
__global__ __launch_bounds__(256)
void k_pass(const float* __restrict__ x,
            const float* tauA, const float* tauD,
            const float* nu, const float* dbreg,
            const float* __restrict__ FYd, const float* __restrict__ FYa,
            const float* __restrict__ FYe,
            float* __restrict__ O0, float* __restrict__ O1) {
  constexpr int FP = FS + 4;
  __shared__ float lds[256 * FP];
  const int t   = threadIdx.x;
  const int blk = blockIdx.x;
  const size_t tileBase = (size_t)blk * (256 * FS);
  const float4* xg = reinterpret_cast<const float4*>(x + tileBase);
#pragma unroll
  for (int i = 0; i < FS / 4; ++i) {
    int idx = t + i * 256;
    float4 v = xg[idx];
    int chunk = (idx * 4) / FS;
    int off   = idx * 4 - chunk * FS;
    *reinterpret_cast<float4*>(&lds[chunk * FP + off]) = v;
  }
  __syncthreads();
  EnvP p = make_params(tauA, tauD, nu, dbreg);
  const int gchunk = blk * 256 + t;
  float* my = &lds[t * FP];
  if (MODE == 0) {
    float A = -INFINITY, B = 0.0f;
#pragma unroll 2
    for (int i = 0; i < FS / 4; ++i) {
      float4 v = *reinterpret_cast<const float4*>(&my[4 * i]);
      float vv[4] = {v.x, v.y, v.z, v.w};
#pragma unroll
      for (int j = 0; j < 4; ++j) {
        float xa = fabsf(vv[j]);
        float bx = p.bd * xa;
        A = fmaxf(xa, fmaf(p.ad, A, bx));
        B = fmaf(p.ad, B, bx);
      }
    }
    O0[gchunk] = A; O1[gchunk] = B;
  } else if (MODE == 1) {
    float yd = FYd[gchunk];
    float A = INFINITY, B = 0.0f;
#pragma unroll 2
    for (int i = 0; i < FS / 4; ++i) {
      float4 v = *reinterpret_cast<const float4*>(&my[4 * i]);
      float vv[4] = {v.x, v.y, v.z, v.w};
#pragma unroll
      for (int j = 0; j < 4; ++j) {
        float xa = fabsf(vv[j]);
        yd = fmaxf(xa, fmaf(p.ad, yd, p.bd * xa));
        float by = p.ba * yd;
        A = fminf(yd, fmaf(p.aa, A, by));
        B = fmaf(p.aa, B, by);
      }
    }
    O0[gchunk] = A; O1[gchunk] = B;
  } else if (MODE == 2) {
    float yd = FYd[gchunk], ya = FYa[gchunk];
    float A = -INFINITY, B = 0.0f;
#pragma unroll 2
    for (int i = 0; i < FS / 4; ++i) {
      float4 v = *reinterpret_cast<const float4*>(&my[4 * i]);
      float vv[4] = {v.x, v.y, v.z, v.w};
#pragma unroll
      for (int j = 0; j < 4; ++j) {
        float xa = fabsf(vv[j]);
        yd = fmaxf(xa, fmaf(p.ad, yd, p.bd * xa));
        ya = fminf(yd, fmaf(p.aa, ya, p.ba * yd));
        float et = fmaxf((yd - ya) - p.nuamp, 0.0f);
        float bx = p.bd * et;
        A = fmaxf(et, fmaf(p.ad, A, bx));
        B = fmaf(p.ad, B, bx);
      }
    }
    O0[gchunk] = A; O1[gchunk] = B;
  } else {
    float yd = FYd[gchunk], ya = FYa[gchunk], ye = FYe[gchunk];
#pragma unroll 2
    for (int i = 0; i < FS / 4; ++i) {
      float4 v = *reinterpret_cast<const float4*>(&my[4 * i]);
      float vv[4] = {v.x, v.y, v.z, v.w};
      float oo[4];
#pragma unroll
      for (int j = 0; j < 4; ++j) {
        float xa = fabsf(vv[j]);
        yd = fmaxf(xa, fmaf(p.ad, yd, p.bd * xa));
        ya = fminf(yd, fmaf(p.aa, ya, p.ba * yd));
        float et = fmaxf((yd - ya) - p.nuamp, 0.0f);
        ye = fmaxf(et, fmaf(p.ad, ye, p.bd * et));
        oo[j] = vv[j] * (et / (ye + p.reg));
      }
      *reinterpret_cast<float4*>(&my[4 * i]) = make_float4(oo[0], oo[1], oo[2], oo[3]);
    }
    __syncthreads();
    float4* og = reinterpret_cast<float4*>(O0 + tileBase);
#pragma unroll
    for (int i = 0; i < FS / 4; ++i) {
      int idx = t + i * 256;
      int chunk = (idx * 4) / FS;
      int off   = idx * 4 - chunk * FS;
      og[idx] = *reinterpret_cast<const float4*>(&lds[chunk * FP + off]);
    }
  }
}

template <int FS, int ATTACK>
__global__ __launch_bounds__(256)
void k_scan(const float* __restrict__ A, const float* __restrict__ B,
            float* __restrict__ Y,
            const float* tauA, const float* tauD,
            const float* nu, const float* dbreg) {
  constexpr int FNC = kT / FS;
  constexpr int CPT = (FNC + 255) / 256;
  EnvP p = make_params(tauA, tauD, nu, dbreg);
  const float alpha = ATTACK ? p.aa : p.ad;
  const float ID_A  = ATTACK ? INFINITY : -INFINITY;
  int s = blockIdx.x, t = threadIdx.x;
  long base = (long)s * FNC;
  float gS = powf(alpha, (float)FS);

  float ca[CPT], cb[CPT];
  float a = ID_A, b = 0.0f, g = 1.0f;
#pragma unroll
  for (int k = 0; k < CPT; ++k) {
    int c = t * CPT + k;
    if (c < FNC) { ca[k] = A[base + c]; cb[k] = B[base + c]; }
    else         { ca[k] = ID_A;        cb[k] = 0.0f; }
    float cg = (c < FNC) ? gS : 1.0f;
    float na = ATTACK ? fminf(ca[k], fmaf(cg, a, cb[k]))
                      : fmaxf(ca[k], fmaf(cg, a, cb[k]));
    b = fmaf(cg, b, cb[k]);
    g = cg * g;
    a = na;
  }

  __shared__ float sA[256], sB[256], sG[256];
  sA[t] = a; sB[t] = b; sG[t] = g;
  __syncthreads();
#pragma unroll
  for (int d = 1; d < 256; d <<= 1) {
    float pa = 0.0f, pb = 0.0f, pg = 0.0f;
    if (t >= d) { pa = sA[t - d]; pb = sB[t - d]; pg = sG[t - d]; }
    __syncthreads();
    if (t >= d) {
      float na = ATTACK ? fminf(a, fmaf(g, pa, b)) : fmaxf(a, fmaf(g, pa, b));
      b = fmaf(g, pb, b);
      g = g * pg;
      a = na;
      sA[t] = a; sB[t] = b; sG[t] = g;
    }
    __syncthreads();
  }

  float ea, eb;
  if (t == 0) { ea = ID_A; eb = 0.0f; }
  else        { ea = sA[t - 1]; eb = sB[t - 1]; }

#pragma unroll
  for (int k = 0; k < CPT; ++k) {
    int c = t * CPT + k;
    if (c >= FNC) break;
    Y[base + c] = ATTACK ? fminf(ea, eb) : fmaxf(ea, eb);
    float na = ATTACK ? fminf(ca[k], fmaf(gS, ea, cb[k]))
                      : fmaxf(ca[k], fmaf(gS, ea, cb[k]));
    eb = fmaf(gS, eb, cb[k]);
    ea = na;
  }
}

template <int FS>
static void run_pipeline(const float* x, const float* tauA, const float* tauD,
                         const float* nu, const float* dbreg, float* out,
                         float* wsf, int nseries, hipStream_t stream) {
  const int nc  = kT / FS;
  const int nch = nseries * nc;
  float* A   = wsf;
  float* B   = wsf + (size_t)nch;
  float* FYd = wsf + (size_t)2 * nch;
  float* FYa = wsf + (size_t)3 * nch;
  float* FYe = wsf + (size_t)4 * nch;
  const int grid = nch / 256;

  k_pass<FS, 0><<<grid, 256, 0, stream>>>(x, tauA, tauD, nu, dbreg, nullptr, nullptr, nullptr, A, B);
  k_scan<FS, 0><<<nseries, 256, 0, stream>>>(A, B, FYd, tauA, tauD, nu, dbreg);
  k_pass<FS, 1><<<grid, 256, 0, stream>>>(x, tauA, tauD, nu, dbreg, FYd, nullptr, nullptr, A, B);
  k_scan<FS, 1><<<nseries, 256, 0, stream>>>(A, B, FYa, tauA, tauD, nu, dbreg);
  k_pass<FS, 2><<<grid, 256, 0, stream>>>(x, tauA, tauD, nu, dbreg, FYd, FYa, nullptr, A, B);
  k_scan<FS, 0><<<nseries, 256, 0, stream>>>(A, B, FYe, tauA, tauD, nu, dbreg);
  k_pass<FS, 3><<<grid, 256, 0, stream>>>(x, tauA, tauD, nu, dbreg, FYd, FYa, FYe, out, nullptr);
}

extern "C" void kernel_launch(void* const* d_in, const int* in_sizes, int n_in,
                              void* d_out, int out_size, void* d_ws, size_t ws_size,
                              hipStream_t stream) {
  const float* x     = (const float*)d_in[0];
  const float* tauA  = (const float*)d_in[1];
  const float* tauD  = (const float*)d_in[2];
  const float* nu    = (const float*)d_in[3];
  const float* dbreg = (const float*)d_in[4];
  float* out = (float*)d_out;
  float* wsf = (float*)d_ws;
  const int nseries = in_sizes[0] / kT;       // 256

  constexpr size_t LDSZ = (size_t)(2 * FBUF_F + 2 * FNC_) * sizeof(float); // 144088 B
  const size_t NS = (size_t)FNC_ * nseries;   // floats per Y array
  const bool wsOK = 3 * NS * sizeof(float) <= ws_size;  // 11,289,600 B

  static int fusedOK = -1;                    // one-time host-side probe
  if (fusedOK < 0) {
    hipFuncSetAttribute(reinterpret_cast<const void*>(&k_one),
                        hipFuncAttributeMaxDynamicSharedMemorySize, (int)LDSZ);
    (void)hipGetLastError();                  // clear any error state
    fusedOK = 1;
  }

  if (fusedOK == 1 && wsOK) {
    float* Yd = wsf;
    float* Ya = wsf + NS;
    float* Ye = wsf + 2 * NS;
    k_one<<<nseries, FTH, LDSZ, stream>>>(x, tauA, tauD, nu, dbreg, Yd, Ya, Ye, out);
    if (hipGetLastError() == hipSuccess) return;
    fusedOK = 0;                              // launch rejected -> pipeline forever
  }

  auto fits = [&](int FS) {
    return (size_t)5 * nseries * (kT / FS) * sizeof(float) <= ws_size;
  };
  if      (fits(40))  run_pipeline<40 >(x, tauA, tauD, nu, dbreg, out, wsf, nseries, stream);
  else if (fits(56))  run_pipeline<56 >(x, tauA, tauD, nu, dbreg, out, wsf, nseries, stream);
  else if (fits(72))  run_pipeline<72 >(x, tauA, tauD, nu, dbreg, out, wsf, nseries, stream);
  else                run_pipeline<120>(x, tauA, tauD, nu, dbreg, out, wsf, nseries, stream);
}